// Round 5
// baseline (739.390 us; speedup 1.0000x reference)
//
#include <hip/hip_runtime.h>
#include <hip/hip_bf16.h>

typedef __bf16 bf16x8_t __attribute__((ext_vector_type(8)));
typedef float f32x4_t __attribute__((ext_vector_type(4)));
using bf16 = __hip_bfloat16;

#define EMB 512
#define NTOK 32768           // B*T = 8*4096
#define NROW 262144          // B*T*H
#define SQRT_M_INV 0.17677669529663687f

// async 16B global -> LDS (wave-uniform base + lane*16; thread-order contiguous)
__device__ __forceinline__ void gload16(const void* g, void* l) {
  __builtin_amdgcn_global_load_lds((const __attribute__((address_space(1))) void*)g,
                                   (__attribute__((address_space(3))) void*)l, 16, 0, 0);
}

// ---------------- fused fp32 -> bf16 for the 4 weight tensors ----------------
__device__ __forceinline__ void cvt4(const float* __restrict__ in,
                                     bf16* __restrict__ out, int i4, int n4) {
  if (i4 < n4) {
    float4 v = ((const float4*)in)[i4];
    alignas(8) bf16 o[4];
    o[0] = __float2bfloat16(v.x); o[1] = __float2bfloat16(v.y);
    o[2] = __float2bfloat16(v.z); o[3] = __float2bfloat16(v.w);
    *(uint2*)(out + i4 * 4) = *(const uint2*)o;
  }
}
__global__ __launch_bounds__(256) void f2b4_kernel(
    const float* __restrict__ a, bf16* __restrict__ oa, int na4,
    const float* __restrict__ b, bf16* __restrict__ ob, int nb4,
    const float* __restrict__ c, bf16* __restrict__ oc, int nc4,
    const float* __restrict__ d, bf16* __restrict__ od, int nd4) {
  int i4 = blockIdx.x * 256 + threadIdx.x;
  cvt4(a, oa, i4, na4);
  cvt4(b, ob, i4, nb4);
  cvt4(c, oc, i4, nc4);
  cvt4(d, od, i4, nd4);
}

// ---------------- LayerNorm (512 cols), fp32 in -> bf16 out ----------------
__global__ __launch_bounds__(256) void ln_kernel(const float* __restrict__ x,
                                                 const float* __restrict__ g,
                                                 const float* __restrict__ bt,
                                                 bf16* __restrict__ out) {
  int lane = threadIdx.x & 63;
  int row = blockIdx.x * 4 + (threadIdx.x >> 6);
  const float* xr = x + (size_t)row * EMB;
  float4 v0 = ((const float4*)xr)[lane * 2];
  float4 v1 = ((const float4*)xr)[lane * 2 + 1];
  float s = v0.x + v0.y + v0.z + v0.w + v1.x + v1.y + v1.z + v1.w;
#pragma unroll
  for (int o = 32; o; o >>= 1) s += __shfl_xor(s, o);
  float mu = s * (1.0f / 512.0f);
  float vs = 0.f, d;
  d = v0.x - mu; vs += d * d;  d = v0.y - mu; vs += d * d;
  d = v0.z - mu; vs += d * d;  d = v0.w - mu; vs += d * d;
  d = v1.x - mu; vs += d * d;  d = v1.y - mu; vs += d * d;
  d = v1.z - mu; vs += d * d;  d = v1.w - mu; vs += d * d;
#pragma unroll
  for (int o = 32; o; o >>= 1) vs += __shfl_xor(vs, o);
  float rstd = rsqrtf(vs * (1.0f / 512.0f) + 1e-5f);
  float4 g0 = ((const float4*)g)[lane * 2], g1 = ((const float4*)g)[lane * 2 + 1];
  float4 b0 = ((const float4*)bt)[lane * 2], b1 = ((const float4*)bt)[lane * 2 + 1];
  alignas(16) bf16 o8[8];
  o8[0] = __float2bfloat16((v0.x - mu) * rstd * g0.x + b0.x);
  o8[1] = __float2bfloat16((v0.y - mu) * rstd * g0.y + b0.y);
  o8[2] = __float2bfloat16((v0.z - mu) * rstd * g0.z + b0.z);
  o8[3] = __float2bfloat16((v0.w - mu) * rstd * g0.w + b0.w);
  o8[4] = __float2bfloat16((v1.x - mu) * rstd * g1.x + b1.x);
  o8[5] = __float2bfloat16((v1.y - mu) * rstd * g1.y + b1.y);
  o8[6] = __float2bfloat16((v1.z - mu) * rstd * g1.z + b1.z);
  o8[7] = __float2bfloat16((v1.w - mu) * rstd * g1.w + b1.w);
  *(uint4*)(out + (size_t)row * EMB + lane * 8) = *(const uint4*)o8;
}

// ---------------- MFMA bf16 GEMM (m97-style): C = A[M,K] * W[N,K]^T ---------
template <int BM, int BN, int WM, int WN, int OP>
__global__ __launch_bounds__(256) void gemm_bt(const bf16* __restrict__ A,
                                               const bf16* __restrict__ W,
                                               const float* __restrict__ bias,
                                               const float* __restrict__ res,
                                               float* __restrict__ outF,
                                               bf16* __restrict__ outB,
                                               int M, int N, int K) {
  constexpr int BK = 32;
  constexpr int TM = BM / WM, TN = BN / WN;
  constexpr int NI = TM / 16, NJ = TN / 16;
  alignas(16) __shared__ bf16 As[BM * BK];
  alignas(16) __shared__ bf16 Ws[BN * BK];
  int t = threadIdx.x;
  int lane = t & 63, wid = t >> 6;
  int wm = wid % WM, wn = wid / WM;
  int bn = blockIdx.x * BN, bm = blockIdx.y * BM;
  int lr = lane & 15, lq = lane >> 4;
  const int r0 = (t * 8) >> 5, c0 = (t * 8) & 31;

  f32x4_t acc[NI][NJ];
#pragma unroll
  for (int i = 0; i < NI; ++i)
#pragma unroll
    for (int j = 0; j < NJ; ++j)
#pragma unroll
      for (int r = 0; r < 4; ++r) acc[i][j][r] = 0.f;

  for (int k0 = 0; k0 < K; k0 += BK) {
#pragma unroll
    for (int p = 0; p < BM * BK / 2048; ++p) {
      int r = r0 + p * 64;
      gload16(&A[(size_t)(bm + r) * K + k0 + c0], &As[r * BK + c0]);
    }
#pragma unroll
    for (int p = 0; p < BN * BK / 2048; ++p) {
      int r = r0 + p * 64;
      gload16(&W[(size_t)(bn + r) * K + k0 + c0], &Ws[r * BK + c0]);
    }
    __syncthreads();
    bf16x8_t afr[NI], bfr[NJ];
#pragma unroll
    for (int i = 0; i < NI; ++i)
      afr[i] = *(const bf16x8_t*)&As[(wm * TM + i * 16 + lr) * BK + lq * 8];
#pragma unroll
    for (int j = 0; j < NJ; ++j)
      bfr[j] = *(const bf16x8_t*)&Ws[(wn * TN + j * 16 + lr) * BK + lq * 8];
#pragma unroll
    for (int i = 0; i < NI; ++i)
#pragma unroll
      for (int j = 0; j < NJ; ++j)
        acc[i][j] = __builtin_amdgcn_mfma_f32_16x16x32_bf16(afr[i], bfr[j], acc[i][j], 0, 0, 0);
    __syncthreads();
  }

#pragma unroll
  for (int i = 0; i < NI; ++i)
#pragma unroll
    for (int j = 0; j < NJ; ++j) {
      int gn = bn + wn * TN + j * 16 + lr;
      float bv = bias[gn];
#pragma unroll
      for (int r = 0; r < 4; ++r) {
        int gm = bm + wm * TM + i * 16 + lq * 4 + r;
        float v = acc[i][j][r] + bv;
        size_t off = (size_t)gm * N + gn;
        if (OP == 0) {
          outF[off] = v;
        } else if (OP == 1) {
          outF[off] = v + res[off];
        } else {
          float gg = 0.5f * v * (1.0f + erff(v * 0.70710678118654752f));
          outB[off] = __float2bfloat16(gg);
        }
      }
    }
}

// ---------------- Fused KQV GEMM + prm_exp (all-MFMA) ------------------------
__global__ __launch_bounds__(256) void kqv_prm_kernel(
    const bf16* __restrict__ A,      // [NROW,64] LN1 out
    const bf16* __restrict__ Wk,     // [192,64]
    const float* __restrict__ bias,  // [192]
    const float* __restrict__ wrf,   // [32,64] random features
    float* __restrict__ kp, float* __restrict__ qp,
    bf16* __restrict__ vout) {       // [NROW,64]
  constexpr int LDZ = 136;  // bf16 elems/row: stride 68 dwords -> 2-way max
  constexpr int LDV = 72;
  alignas(16) __shared__ char u_raw[27648];
  bf16* As  = (bf16*)u_raw;               // phase1: 64*32*2  = 4096
  bf16* Ws  = (bf16*)(u_raw + 4096);      // phase1: 192*32*2 = 12288
  bf16* zkq = (bf16*)u_raw;               // phase2: 64*136*2 = 17408
  bf16* vs  = (bf16*)(u_raw + 17408);     // phase2: 64*72*2  = 9216
  float* xd_s = (float*)(u_raw + 26624);  // phase2: 64*2*4   = 512

  int t = threadIdx.x;
  int lane = t & 63, wid = t >> 6;
  int wm = wid & 1, wn = wid >> 1;
  int lr = lane & 15, lq = lane >> 4;
  size_t row0 = (size_t)blockIdx.x * 64;

  bf16x8_t wfrag[2][2];
#pragma unroll
  for (int mt = 0; mt < 2; ++mt)
#pragma unroll
    for (int ks = 0; ks < 2; ++ks) {
      const float* src = wrf + (mt * 16 + lr) * 64 + ks * 32 + lq * 8;
#pragma unroll
      for (int jj = 0; jj < 8; ++jj) wfrag[mt][ks][jj] = (__bf16)src[jj];
    }

  f32x4_t acc[2][6];
#pragma unroll
  for (int i = 0; i < 2; ++i)
#pragma unroll
    for (int j = 0; j < 6; ++j)
#pragma unroll
      for (int r = 0; r < 4; ++r) acc[i][j][r] = 0.f;

  const int r0 = t >> 2, c0 = (t * 8) & 31;
  for (int k0 = 0; k0 < 64; k0 += 32) {
    gload16(&A[(row0 + r0) * 64 + k0 + c0], &As[r0 * 32 + c0]);
#pragma unroll
    for (int p = 0; p < 3; ++p) {
      int r = r0 + p * 64;
      gload16(&Wk[(size_t)r * 64 + k0 + c0], &Ws[r * 32 + c0]);
    }
    __syncthreads();
    bf16x8_t af[2], bfr[6];
#pragma unroll
    for (int i = 0; i < 2; ++i)
      af[i] = *(const bf16x8_t*)&As[(wm * 32 + i * 16 + lr) * 32 + lq * 8];
#pragma unroll
    for (int j = 0; j < 6; ++j)
      bfr[j] = *(const bf16x8_t*)&Ws[(wn * 96 + j * 16 + lr) * 32 + lq * 8];
#pragma unroll
    for (int i = 0; i < 2; ++i)
#pragma unroll
      for (int j = 0; j < 6; ++j)
        acc[i][j] = __builtin_amdgcn_mfma_f32_16x16x32_bf16(af[i], bfr[j], acc[i][j], 0, 0, 0);
    __syncthreads();
  }

#pragma unroll
  for (int i = 0; i < 2; ++i)
#pragma unroll
    for (int j = 0; j < 6; ++j) {
      int col = wn * 96 + j * 16 + lr;
      float bv = bias[col];
      int rowb = wm * 32 + i * 16 + lq * 4;
#pragma unroll
      for (int r = 0; r < 4; ++r) {
        float v = acc[i][j][r] + bv;
        if (col < 128) zkq[(rowb + r) * LDZ + col] = __float2bfloat16(v);
        else           vs[(rowb + r) * LDV + (col - 128)] = __float2bfloat16(v);
      }
    }
  __syncthreads();

  if (t < 128) {
    int r = t & 63, sel = t >> 6;
    const bf16* zr = &zkq[r * LDZ + sel * 64];
    float xd = 0.f;
#pragma unroll
    for (int c = 0; c < 64; c += 8) {
      bf16x8_t z8 = *(const bf16x8_t*)&zr[c];
#pragma unroll
      for (int jj = 0; jj < 8; ++jj) { float f = (float)z8[jj]; xd += f * f; }
    }
    xd_s[r * 2 + sel] = 0.5f * xd;
  }
  __syncthreads();

#pragma unroll
  for (int p = 0; p < 2; ++p) {
    int idx = t + p * 256;            // 512 uint4s = 64 rows x 8
    int r = idx >> 3, c8 = idx & 7;
    *(uint4*)&vout[(row0 + r) * 64 + c8 * 8] = *(const uint4*)&vs[r * LDV + c8 * 8];
  }

  int sel = wn;
  f32x4_t aw[2][2];
#pragma unroll
  for (int i = 0; i < 2; ++i)
#pragma unroll
    for (int mt = 0; mt < 2; ++mt)
#pragma unroll
      for (int r = 0; r < 4; ++r) aw[i][mt][r] = 0.f;
#pragma unroll
  for (int ks = 0; ks < 2; ++ks) {
    bf16x8_t af2[2];
#pragma unroll
    for (int i = 0; i < 2; ++i)
      af2[i] = *(const bf16x8_t*)&zkq[(wm * 32 + i * 16 + lr) * LDZ + sel * 64 + ks * 32 + lq * 8];
#pragma unroll
    for (int i = 0; i < 2; ++i)
#pragma unroll
      for (int mt = 0; mt < 2; ++mt)
        aw[i][mt] = __builtin_amdgcn_mfma_f32_16x16x32_bf16(af2[i], wfrag[mt][ks], aw[i][mt], 0, 0, 0);
  }
  float* outp = sel ? qp : kp;
#pragma unroll
  for (int i = 0; i < 2; ++i)
#pragma unroll
    for (int mt = 0; mt < 2; ++mt) {
      int m = mt * 16 + lr;
#pragma unroll
      for (int r = 0; r < 4; ++r) {
        int row = wm * 32 + i * 16 + lq * 4 + r;
        outp[(row0 + row) * 32 + m] =
            __expf(aw[i][mt][r] - xd_s[row * 2 + sel]) * SQRT_M_INV;
      }
    }
}

// ---------------- kptv + kp_sum reduction over T -----------------------------
// No LDS, no barriers (R4: 2 barriers per 8 tokens made this latency-bound at
// 133 us, VALUBusy 11%). Thread (e,g): lane e reads v[tok][e] coalesced; all
// lanes of wave g read the SAME kp float4s (wave-uniform -> L1 broadcast).
// kpsum accumulated redundantly in all lanes (free VALU), atomic from lane 0.
__global__ __launch_bounds__(256) void kptv_kernel(const bf16* __restrict__ v,
                                                   const float* __restrict__ kp,
                                                   float* __restrict__ kptv,
                                                   float* __restrict__ kpsum) {
  int bh = blockIdx.x, chunk = blockIdx.y;   // grid (64, 16); 256 tokens/chunk
  int b = bh >> 3, h = bh & 7;
  int t = threadIdx.x, e = t & 63, g = t >> 6;
  float acc[8] = {0.f, 0.f, 0.f, 0.f, 0.f, 0.f, 0.f, 0.f};
  float accs[8] = {0.f, 0.f, 0.f, 0.f, 0.f, 0.f, 0.f, 0.f};
  size_t rbase = ((size_t)b * 4096 + chunk * 256) * 8 + h;
  const bf16* vp = v + rbase * 64 + e;
  const float* kpp = kp + rbase * 32 + g * 8;
#pragma unroll 4
  for (int tok = 0; tok < 256; ++tok) {
    float vv = __bfloat162float(vp[(size_t)tok * 512]);
    float4 k0 = *(const float4*)(kpp + (size_t)tok * 256);
    float4 k1 = *(const float4*)(kpp + (size_t)tok * 256 + 4);
    acc[0] += vv * k0.x; acc[1] += vv * k0.y; acc[2] += vv * k0.z; acc[3] += vv * k0.w;
    acc[4] += vv * k1.x; acc[5] += vv * k1.y; acc[6] += vv * k1.z; acc[7] += vv * k1.w;
    accs[0] += k0.x; accs[1] += k0.y; accs[2] += k0.z; accs[3] += k0.w;
    accs[4] += k1.x; accs[5] += k1.y; accs[6] += k1.z; accs[7] += k1.w;
  }
  size_t basep = ((size_t)bh * 64 + e) * 32 + g * 8;
#pragma unroll
  for (int j = 0; j < 8; ++j) atomicAdd(&kptv[basep + j], acc[j]);
  if (e == 0) {
#pragma unroll
    for (int j = 0; j < 8; ++j) atomicAdd(&kpsum[bh * 32 + g * 8 + j], accs[j]);
  }
}

// ---------------- y = (qp . kptv) / (qp . kpsum), bf16 out -------------------
__global__ __launch_bounds__(256) void y_kernel(const float* __restrict__ qp,
                                                const float* __restrict__ kptv,
                                                const float* __restrict__ kpsum,
                                                bf16* __restrict__ y) {
  int bh = blockIdx.x, chunk = blockIdx.y;
  int b = bh >> 3, h = bh & 7;
  alignas(16) __shared__ float qp_s[16][32];
  int t = threadIdx.x;
  int e = t & 63, iq = t >> 6;
  float kv[32], ks[32];
  {
    const float* kr = kptv + ((size_t)bh * 64 + e) * 32;
    const float* sr = kpsum + bh * 32;
#pragma unroll
    for (int m = 0; m < 32; m += 4) {
      float4 a = *(const float4*)&kr[m];
      kv[m] = a.x; kv[m + 1] = a.y; kv[m + 2] = a.z; kv[m + 3] = a.w;
      float4 s = *(const float4*)&sr[m];
      ks[m] = s.x; ks[m + 1] = s.y; ks[m + 2] = s.z; ks[m + 3] = s.w;
    }
  }
  for (int grp = 0; grp < 32; ++grp) {
    int tok0 = chunk * 512 + grp * 16;
    __syncthreads();
    if (t < 128) {
      int r = t >> 3, c4 = t & 7;
      size_t grow = ((size_t)(b * 4096 + tok0 + r) * 8 + h);
      *(float4*)&qp_s[r][c4 * 4] = *(const float4*)(qp + grow * 32 + c4 * 4);
    }
    __syncthreads();
#pragma unroll
    for (int i0 = 0; i0 < 4; ++i0) {
      int i = iq * 4 + i0;
      float dot = 0.f, dd = 0.f;
#pragma unroll
      for (int m = 0; m < 32; m += 4) {
        float4 qq = *(const float4*)&qp_s[i][m];
        dot += qq.x * kv[m] + qq.y * kv[m + 1] + qq.z * kv[m + 2] + qq.w * kv[m + 3];
        dd  += qq.x * ks[m] + qq.y * ks[m + 1] + qq.z * ks[m + 2] + qq.w * ks[m + 3];
      }
      y[(size_t)(b * 4096 + tok0 + i) * EMB + h * 64 + e] = __float2bfloat16(dot / dd);
    }
  }
}

extern "C" void kernel_launch(void* const* d_in, const int* in_sizes, int n_in,
                              void* d_out, int out_size, void* d_ws, size_t ws_size,
                              hipStream_t stream) {
  const float* x      = (const float*)d_in[0];
  const float* w      = (const float*)d_in[1];
  const float* kqv_w  = (const float*)d_in[2];
  const float* kqv_b  = (const float*)d_in[3];
  const float* proj_w = (const float*)d_in[4];
  const float* proj_b = (const float*)d_in[5];
  const float* ln1_g  = (const float*)d_in[6];
  const float* ln1_b  = (const float*)d_in[7];
  const float* ln2_g  = (const float*)d_in[8];
  const float* ln2_b  = (const float*)d_in[9];
  const float* mlp_w1 = (const float*)d_in[10];
  const float* mlp_b1 = (const float*)d_in[11];
  const float* mlp_w2 = (const float*)d_in[12];
  const float* mlp_b2 = (const float*)d_in[13];
  float* out = (float*)d_out;

  char* ws = (char*)d_ws;
  size_t off = 0;
  auto alloc = [&](size_t bytes) -> void* {
    void* p = ws + off;
    off = (off + bytes + 255) & ~(size_t)255;
    return p;
  };

  // ~133 MiB total
  bf16* kqv_wb  = (bf16*)alloc(12288 * 2);
  bf16* proj_wb = (bf16*)alloc(262144 * 2);
  bf16* w1b     = (bf16*)alloc(1048576 * 2);
  bf16* w2b     = (bf16*)alloc(1048576 * 2);
  bf16* hb      = (bf16*)alloc((size_t)NTOK * EMB * 2);   // LN1 out; reused as y
  bf16* yb      = hb;
  float* qpb    = (float*)alloc((size_t)NROW * 32 * 4);   // reused as h2 (bf16)
  bf16* h2b     = (bf16*)qpb;
  float* kpb    = (float*)alloc((size_t)NROW * 32 * 4);   // kp; +vb reused as hid
  bf16* hidb    = (bf16*)kpb;                              // spans kpb+vb (67 MB)
  bf16* vb      = (bf16*)alloc((size_t)NROW * 64 * 2);     // contiguous after kpb
  float* kptvb  = (float*)alloc(64 * 64 * 32 * 4);
  float* kpsumb = (float*)alloc(64 * 32 * 4);              // contiguous after kptvb

  // 1) weights -> bf16 (single fused launch; 4 elems/thread via float4)
  f2b4_kernel<<<1024, 256, 0, stream>>>(kqv_w, kqv_wb, 12288 / 4,
                                        proj_w, proj_wb, 262144 / 4,
                                        mlp_w1, w1b, 1048576 / 4,
                                        mlp_w2, w2b, 1048576 / 4);

  // 2) LN1: x -> h (bf16)
  ln_kernel<<<NTOK / 4, 256, 0, stream>>>(x, ln1_g, ln1_b, hb);

  // 3) fused KQV GEMM + prm_exp -> kp, qp (fp32), v (bf16)
  kqv_prm_kernel<<<NROW / 64, 256, 0, stream>>>(hb, kqv_wb, kqv_b, w, kpb, qpb, vb);

  // 4) kptv + kp_sum (atomic accumulate; zero first)
  hipMemsetAsync(kptvb, 0, (size_t)64 * 64 * 32 * 4 + 64 * 32 * 4, stream);
  kptv_kernel<<<dim3(64, 16), 256, 0, stream>>>(vb, kpb, kptvb, kpsumb);

  // 5) y (bf16, token-major [NTOK, 512]) -> reuses hb
  y_kernel<<<dim3(64, 8), 256, 0, stream>>>(qpb, kptvb, kpsumb, yb);

  // 6) proj GEMM + residual: d_out = y @ proj_w^T + proj_b + x
  gemm_bt<128, 128, 2, 2, 1><<<dim3(4, NTOK / 128), 256, 0, stream>>>(
      yb, proj_wb, proj_b, x, out, nullptr, NTOK, 512, 512);

  // 7) LN2: d_out -> h2 (bf16, reuses qp region)
  ln_kernel<<<NTOK / 4, 256, 0, stream>>>(out, ln2_g, ln2_b, h2b);

  // 8) MLP in 2 token-chunks of 16384 (hid reuses kp+v regions, 67 MB)
  for (int c = 0; c < 2; ++c) {
    const bf16* h2c = h2b + (size_t)c * 16384 * 512;
    float* outc = out + (size_t)c * 16384 * 512;
    gemm_bt<128, 128, 2, 2, 2><<<dim3(16, 128), 256, 0, stream>>>(
        h2c, w1b, mlp_b1, nullptr, nullptr, hidb, 16384, 2048, 512);
    gemm_bt<128, 128, 2, 2, 1><<<dim3(4, 128), 256, 0, stream>>>(
        hidb, w2b, mlp_b2, outc, outc, nullptr, 16384, 512, 2048);
  }
}

// Round 6
// 662.419 us; speedup vs baseline: 1.1162x; 1.1162x over previous
//
#include <hip/hip_runtime.h>
#include <hip/hip_bf16.h>

typedef __bf16 bf16x8_t __attribute__((ext_vector_type(8)));
typedef float f32x4_t __attribute__((ext_vector_type(4)));
using bf16 = __hip_bfloat16;

#define EMB 512
#define NTOK 32768           // B*T = 8*4096
#define NROW 262144          // B*T*H
#define SQRT_M_INV 0.17677669529663687f

// async 16B global -> LDS (wave-uniform base + lane*16; thread-order contiguous)
__device__ __forceinline__ void gload16(const void* g, void* l) {
  __builtin_amdgcn_global_load_lds((const __attribute__((address_space(1))) void*)g,
                                   (__attribute__((address_space(3))) void*)l, 16, 0, 0);
}

// ---------------- fused fp32 -> bf16 for the 4 weight tensors ----------------
__device__ __forceinline__ void cvt4(const float* __restrict__ in,
                                     bf16* __restrict__ out, int i4, int n4) {
  if (i4 < n4) {
    float4 v = ((const float4*)in)[i4];
    alignas(8) bf16 o[4];
    o[0] = __float2bfloat16(v.x); o[1] = __float2bfloat16(v.y);
    o[2] = __float2bfloat16(v.z); o[3] = __float2bfloat16(v.w);
    *(uint2*)(out + i4 * 4) = *(const uint2*)o;
  }
}
__global__ __launch_bounds__(256) void f2b4_kernel(
    const float* __restrict__ a, bf16* __restrict__ oa, int na4,
    const float* __restrict__ b, bf16* __restrict__ ob, int nb4,
    const float* __restrict__ c, bf16* __restrict__ oc, int nc4,
    const float* __restrict__ d, bf16* __restrict__ od, int nd4) {
  int i4 = blockIdx.x * 256 + threadIdx.x;
  cvt4(a, oa, i4, na4);
  cvt4(b, ob, i4, nb4);
  cvt4(c, oc, i4, nc4);
  cvt4(d, od, i4, nd4);
}

// ---------------- LayerNorm (512 cols), fp32 in -> bf16 out ----------------
__global__ __launch_bounds__(256) void ln_kernel(const float* __restrict__ x,
                                                 const float* __restrict__ g,
                                                 const float* __restrict__ bt,
                                                 bf16* __restrict__ out) {
  int lane = threadIdx.x & 63;
  int row = blockIdx.x * 4 + (threadIdx.x >> 6);
  const float* xr = x + (size_t)row * EMB;
  float4 v0 = ((const float4*)xr)[lane * 2];
  float4 v1 = ((const float4*)xr)[lane * 2 + 1];
  float s = v0.x + v0.y + v0.z + v0.w + v1.x + v1.y + v1.z + v1.w;
#pragma unroll
  for (int o = 32; o; o >>= 1) s += __shfl_xor(s, o);
  float mu = s * (1.0f / 512.0f);
  float vs = 0.f, d;
  d = v0.x - mu; vs += d * d;  d = v0.y - mu; vs += d * d;
  d = v0.z - mu; vs += d * d;  d = v0.w - mu; vs += d * d;
  d = v1.x - mu; vs += d * d;  d = v1.y - mu; vs += d * d;
  d = v1.z - mu; vs += d * d;  d = v1.w - mu; vs += d * d;
#pragma unroll
  for (int o = 32; o; o >>= 1) vs += __shfl_xor(vs, o);
  float rstd = rsqrtf(vs * (1.0f / 512.0f) + 1e-5f);
  float4 g0 = ((const float4*)g)[lane * 2], g1 = ((const float4*)g)[lane * 2 + 1];
  float4 b0 = ((const float4*)bt)[lane * 2], b1 = ((const float4*)bt)[lane * 2 + 1];
  alignas(16) bf16 o8[8];
  o8[0] = __float2bfloat16((v0.x - mu) * rstd * g0.x + b0.x);
  o8[1] = __float2bfloat16((v0.y - mu) * rstd * g0.y + b0.y);
  o8[2] = __float2bfloat16((v0.z - mu) * rstd * g0.z + b0.z);
  o8[3] = __float2bfloat16((v0.w - mu) * rstd * g0.w + b0.w);
  o8[4] = __float2bfloat16((v1.x - mu) * rstd * g1.x + b1.x);
  o8[5] = __float2bfloat16((v1.y - mu) * rstd * g1.y + b1.y);
  o8[6] = __float2bfloat16((v1.z - mu) * rstd * g1.z + b1.z);
  o8[7] = __float2bfloat16((v1.w - mu) * rstd * g1.w + b1.w);
  *(uint4*)(out + (size_t)row * EMB + lane * 8) = *(const uint4*)o8;
}

// ---------------- MFMA bf16 GEMM (m97-style): C = A[M,K] * W[N,K]^T ---------
template <int BM, int BN, int WM, int WN, int OP>
__global__ __launch_bounds__(256) void gemm_bt(const bf16* __restrict__ A,
                                               const bf16* __restrict__ W,
                                               const float* __restrict__ bias,
                                               const float* __restrict__ res,
                                               float* __restrict__ outF,
                                               bf16* __restrict__ outB,
                                               int M, int N, int K) {
  constexpr int BK = 32;
  constexpr int TM = BM / WM, TN = BN / WN;
  constexpr int NI = TM / 16, NJ = TN / 16;
  alignas(16) __shared__ bf16 As[BM * BK];
  alignas(16) __shared__ bf16 Ws[BN * BK];
  int t = threadIdx.x;
  int lane = t & 63, wid = t >> 6;
  int wm = wid % WM, wn = wid / WM;
  int bn = blockIdx.x * BN, bm = blockIdx.y * BM;
  int lr = lane & 15, lq = lane >> 4;
  const int r0 = (t * 8) >> 5, c0 = (t * 8) & 31;

  f32x4_t acc[NI][NJ];
#pragma unroll
  for (int i = 0; i < NI; ++i)
#pragma unroll
    for (int j = 0; j < NJ; ++j)
#pragma unroll
      for (int r = 0; r < 4; ++r) acc[i][j][r] = 0.f;

  for (int k0 = 0; k0 < K; k0 += BK) {
#pragma unroll
    for (int p = 0; p < BM * BK / 2048; ++p) {
      int r = r0 + p * 64;
      gload16(&A[(size_t)(bm + r) * K + k0 + c0], &As[r * BK + c0]);
    }
#pragma unroll
    for (int p = 0; p < BN * BK / 2048; ++p) {
      int r = r0 + p * 64;
      gload16(&W[(size_t)(bn + r) * K + k0 + c0], &Ws[r * BK + c0]);
    }
    __syncthreads();
    bf16x8_t afr[NI], bfr[NJ];
#pragma unroll
    for (int i = 0; i < NI; ++i)
      afr[i] = *(const bf16x8_t*)&As[(wm * TM + i * 16 + lr) * BK + lq * 8];
#pragma unroll
    for (int j = 0; j < NJ; ++j)
      bfr[j] = *(const bf16x8_t*)&Ws[(wn * TN + j * 16 + lr) * BK + lq * 8];
#pragma unroll
    for (int i = 0; i < NI; ++i)
#pragma unroll
      for (int j = 0; j < NJ; ++j)
        acc[i][j] = __builtin_amdgcn_mfma_f32_16x16x32_bf16(afr[i], bfr[j], acc[i][j], 0, 0, 0);
    __syncthreads();
  }

#pragma unroll
  for (int i = 0; i < NI; ++i)
#pragma unroll
    for (int j = 0; j < NJ; ++j) {
      int gn = bn + wn * TN + j * 16 + lr;
      float bv = bias[gn];
#pragma unroll
      for (int r = 0; r < 4; ++r) {
        int gm = bm + wm * TM + i * 16 + lq * 4 + r;
        float v = acc[i][j][r] + bv;
        size_t off = (size_t)gm * N + gn;
        if (OP == 0) {
          outF[off] = v;
        } else if (OP == 1) {
          outF[off] = v + res[off];
        } else {
          float gg = 0.5f * v * (1.0f + erff(v * 0.70710678118654752f));
          outB[off] = __float2bfloat16(gg);
        }
      }
    }
}

// decompose global kqv row (b*4096+t)*8+h -> per-(b,h) contiguous row (b*8+h)*4096+t
__device__ __forceinline__ size_t bh_row(size_t grow) {
  size_t h = grow & 7, bt = grow >> 3;
  size_t b = bt >> 12, tt = bt & 4095;
  return ((b * 8 + h) << 12) + tt;
}

// ---------------- Fused KQV GEMM + prm_exp (all-MFMA) ------------------------
// kp/qp/v written in per-(b,h) contiguous layout: [64 bh][4096 t][{32|64}].
__global__ __launch_bounds__(256) void kqv_prm_kernel(
    const bf16* __restrict__ A,      // [NROW,64] LN1 out
    const bf16* __restrict__ Wk,     // [192,64]
    const float* __restrict__ bias,  // [192]
    const float* __restrict__ wrf,   // [32,64] random features
    float* __restrict__ kp, float* __restrict__ qp,   // [64][4096][32]
    bf16* __restrict__ vout) {                        // [64][4096][64]
  constexpr int LDZ = 136;  // bf16 elems/row: stride 68 dwords -> 2-way max
  constexpr int LDV = 72;
  alignas(16) __shared__ char u_raw[27648];
  bf16* As  = (bf16*)u_raw;               // phase1: 64*32*2  = 4096
  bf16* Ws  = (bf16*)(u_raw + 4096);      // phase1: 192*32*2 = 12288
  bf16* zkq = (bf16*)u_raw;               // phase2: 64*136*2 = 17408
  bf16* vs  = (bf16*)(u_raw + 17408);     // phase2: 64*72*2  = 9216
  float* xd_s = (float*)(u_raw + 26624);  // phase2: 64*2*4   = 512

  int t = threadIdx.x;
  int lane = t & 63, wid = t >> 6;
  int wm = wid & 1, wn = wid >> 1;
  int lr = lane & 15, lq = lane >> 4;
  size_t row0 = (size_t)blockIdx.x * 64;

  bf16x8_t wfrag[2][2];
#pragma unroll
  for (int mt = 0; mt < 2; ++mt)
#pragma unroll
    for (int ks = 0; ks < 2; ++ks) {
      const float* src = wrf + (mt * 16 + lr) * 64 + ks * 32 + lq * 8;
#pragma unroll
      for (int jj = 0; jj < 8; ++jj) wfrag[mt][ks][jj] = (__bf16)src[jj];
    }

  f32x4_t acc[2][6];
#pragma unroll
  for (int i = 0; i < 2; ++i)
#pragma unroll
    for (int j = 0; j < 6; ++j)
#pragma unroll
      for (int r = 0; r < 4; ++r) acc[i][j][r] = 0.f;

  const int r0 = t >> 2, c0 = (t * 8) & 31;
  for (int k0 = 0; k0 < 64; k0 += 32) {
    gload16(&A[(row0 + r0) * 64 + k0 + c0], &As[r0 * 32 + c0]);
#pragma unroll
    for (int p = 0; p < 3; ++p) {
      int r = r0 + p * 64;
      gload16(&Wk[(size_t)r * 64 + k0 + c0], &Ws[r * 32 + c0]);
    }
    __syncthreads();
    bf16x8_t af[2], bfr[6];
#pragma unroll
    for (int i = 0; i < 2; ++i)
      af[i] = *(const bf16x8_t*)&As[(wm * 32 + i * 16 + lr) * 32 + lq * 8];
#pragma unroll
    for (int j = 0; j < 6; ++j)
      bfr[j] = *(const bf16x8_t*)&Ws[(wn * 96 + j * 16 + lr) * 32 + lq * 8];
#pragma unroll
    for (int i = 0; i < 2; ++i)
#pragma unroll
      for (int j = 0; j < 6; ++j)
        acc[i][j] = __builtin_amdgcn_mfma_f32_16x16x32_bf16(af[i], bfr[j], acc[i][j], 0, 0, 0);
    __syncthreads();
  }

#pragma unroll
  for (int i = 0; i < 2; ++i)
#pragma unroll
    for (int j = 0; j < 6; ++j) {
      int col = wn * 96 + j * 16 + lr;
      float bv = bias[col];
      int rowb = wm * 32 + i * 16 + lq * 4;
#pragma unroll
      for (int r = 0; r < 4; ++r) {
        float v = acc[i][j][r] + bv;
        if (col < 128) zkq[(rowb + r) * LDZ + col] = __float2bfloat16(v);
        else           vs[(rowb + r) * LDV + (col - 128)] = __float2bfloat16(v);
      }
    }
  __syncthreads();

  if (t < 128) {
    int r = t & 63, sel = t >> 6;
    const bf16* zr = &zkq[r * LDZ + sel * 64];
    float xd = 0.f;
#pragma unroll
    for (int c = 0; c < 64; c += 8) {
      bf16x8_t z8 = *(const bf16x8_t*)&zr[c];
#pragma unroll
      for (int jj = 0; jj < 8; ++jj) { float f = (float)z8[jj]; xd += f * f; }
    }
    xd_s[r * 2 + sel] = 0.5f * xd;
  }
  __syncthreads();

  // v -> global, per-(b,h) layout
#pragma unroll
  for (int p = 0; p < 2; ++p) {
    int idx = t + p * 256;            // 512 uint4s = 64 rows x 8
    int r = idx >> 3, c8 = idx & 7;
    size_t nr = bh_row(row0 + r);
    *(uint4*)&vout[nr * 64 + c8 * 8] = *(const uint4*)&vs[r * LDV + c8 * 8];
  }

  int sel = wn;
  f32x4_t aw[2][2];
#pragma unroll
  for (int i = 0; i < 2; ++i)
#pragma unroll
    for (int mt = 0; mt < 2; ++mt)
#pragma unroll
      for (int r = 0; r < 4; ++r) aw[i][mt][r] = 0.f;
#pragma unroll
  for (int ks = 0; ks < 2; ++ks) {
    bf16x8_t af2[2];
#pragma unroll
    for (int i = 0; i < 2; ++i)
      af2[i] = *(const bf16x8_t*)&zkq[(wm * 32 + i * 16 + lr) * LDZ + sel * 64 + ks * 32 + lq * 8];
#pragma unroll
    for (int i = 0; i < 2; ++i)
#pragma unroll
      for (int mt = 0; mt < 2; ++mt)
        aw[i][mt] = __builtin_amdgcn_mfma_f32_16x16x32_bf16(af2[i], wfrag[mt][ks], aw[i][mt], 0, 0, 0);
  }
  float* outp = sel ? qp : kp;
#pragma unroll
  for (int i = 0; i < 2; ++i)
#pragma unroll
    for (int r = 0; r < 4; ++r) {
      int row = wm * 32 + i * 16 + lq * 4 + r;
      size_t nr = bh_row(row0 + row);
#pragma unroll
      for (int mt = 0; mt < 2; ++mt) {
        int m = mt * 16 + lr;
        outp[nr * 32 + m] =
            __expf(aw[i][mt][r] - xd_s[row * 2 + sel]) * SQRT_M_INV;
      }
    }
}

// ---------------- kptv + kp_sum partial reduction over T ---------------------
// NO atomics (R5: 2M device atomics = 65 MB HBM RMW writes, 166 us). Each
// block (bh, chunk of 512 tokens) accumulates in registers and stores a plain
// partial [64e x 32m] + [32 kpsum] -> part[bh*8+chunk][2080]. v2/kp2 are
// per-(b,h) contiguous so all loads stream.
__global__ __launch_bounds__(256) void kptv_kernel(const bf16* __restrict__ v2,
                                                   const float* __restrict__ kp2,
                                                   float* __restrict__ part) {
  int bh = blockIdx.x, chunk = blockIdx.y;   // grid (64, 8)
  int t = threadIdx.x, e = t & 63, g = t >> 6;
  const bf16* vp = v2 + ((size_t)bh * 4096 + chunk * 512) * 64 + e;
  const float* kpp = kp2 + ((size_t)bh * 4096 + chunk * 512) * 32 + g * 8;
  float acc[8] = {0.f, 0.f, 0.f, 0.f, 0.f, 0.f, 0.f, 0.f};
  float accs[8] = {0.f, 0.f, 0.f, 0.f, 0.f, 0.f, 0.f, 0.f};
#pragma unroll 8
  for (int tok = 0; tok < 512; ++tok) {
    float vv = __bfloat162float(vp[tok * 64]);
    float4 k0 = *(const float4*)(kpp + tok * 32);
    float4 k1 = *(const float4*)(kpp + tok * 32 + 4);
    acc[0] += vv * k0.x; acc[1] += vv * k0.y; acc[2] += vv * k0.z; acc[3] += vv * k0.w;
    acc[4] += vv * k1.x; acc[5] += vv * k1.y; acc[6] += vv * k1.z; acc[7] += vv * k1.w;
    accs[0] += k0.x; accs[1] += k0.y; accs[2] += k0.z; accs[3] += k0.w;
    accs[4] += k1.x; accs[5] += k1.y; accs[6] += k1.z; accs[7] += k1.w;
  }
  float* pp = part + (size_t)(bh * 8 + chunk) * 2080 + e * 32 + g * 8;
  *(float4*)pp = make_float4(acc[0], acc[1], acc[2], acc[3]);
  *(float4*)(pp + 4) = make_float4(acc[4], acc[5], acc[6], acc[7]);
  if (e == 0) {
    float* ps = part + (size_t)(bh * 8 + chunk) * 2080 + 2048 + g * 8;
    *(float4*)ps = make_float4(accs[0], accs[1], accs[2], accs[3]);
    *(float4*)(ps + 4) = make_float4(accs[4], accs[5], accs[6], accs[7]);
  }
}

// ---------------- y = (qp . kptv) / (qp . kpsum), bf16 out -------------------
// Preamble sums the 8 per-chunk partials into registers (L2/L3-warm).
__global__ __launch_bounds__(256) void y_kernel(const float* __restrict__ qp2,
                                                const float* __restrict__ part,
                                                bf16* __restrict__ y) {
  int bh = blockIdx.x, chunk = blockIdx.y;   // grid (64, 8)
  int b = bh >> 3, h = bh & 7;
  alignas(16) __shared__ float qp_s[16][32];
  int t = threadIdx.x;
  int e = t & 63, iq = t >> 6;
  float kv[32], ks[32];
#pragma unroll
  for (int m = 0; m < 32; ++m) { kv[m] = 0.f; ks[m] = 0.f; }
  for (int c = 0; c < 8; ++c) {
    const float* pp = part + (size_t)(bh * 8 + c) * 2080;
#pragma unroll
    for (int m = 0; m < 32; m += 4) {
      float4 a = *(const float4*)&pp[e * 32 + m];
      kv[m] += a.x; kv[m + 1] += a.y; kv[m + 2] += a.z; kv[m + 3] += a.w;
      float4 s = *(const float4*)&pp[2048 + m];
      ks[m] += s.x; ks[m + 1] += s.y; ks[m + 2] += s.z; ks[m + 3] += s.w;
    }
  }
  for (int grp = 0; grp < 32; ++grp) {
    int tok0 = chunk * 512 + grp * 16;
    __syncthreads();
    if (t < 128) {
      int r = t >> 3, c4 = t & 7;
      *(float4*)&qp_s[r][c4 * 4] =
          *(const float4*)(qp2 + ((size_t)bh * 4096 + tok0 + r) * 32 + c4 * 4);
    }
    __syncthreads();
#pragma unroll
    for (int i0 = 0; i0 < 4; ++i0) {
      int i = iq * 4 + i0;
      float dot = 0.f, dd = 0.f;
#pragma unroll
      for (int m = 0; m < 32; m += 4) {
        float4 qq = *(const float4*)&qp_s[i][m];
        dot += qq.x * kv[m] + qq.y * kv[m + 1] + qq.z * kv[m + 2] + qq.w * kv[m + 3];
        dd  += qq.x * ks[m] + qq.y * ks[m + 1] + qq.z * ks[m + 2] + qq.w * ks[m + 3];
      }
      y[(size_t)(b * 4096 + tok0 + i) * EMB + h * 64 + e] = __float2bfloat16(dot / dd);
    }
  }
}

extern "C" void kernel_launch(void* const* d_in, const int* in_sizes, int n_in,
                              void* d_out, int out_size, void* d_ws, size_t ws_size,
                              hipStream_t stream) {
  const float* x      = (const float*)d_in[0];
  const float* w      = (const float*)d_in[1];
  const float* kqv_w  = (const float*)d_in[2];
  const float* kqv_b  = (const float*)d_in[3];
  const float* proj_w = (const float*)d_in[4];
  const float* proj_b = (const float*)d_in[5];
  const float* ln1_g  = (const float*)d_in[6];
  const float* ln1_b  = (const float*)d_in[7];
  const float* ln2_g  = (const float*)d_in[8];
  const float* ln2_b  = (const float*)d_in[9];
  const float* mlp_w1 = (const float*)d_in[10];
  const float* mlp_b1 = (const float*)d_in[11];
  const float* mlp_w2 = (const float*)d_in[12];
  const float* mlp_b2 = (const float*)d_in[13];
  float* out = (float*)d_out;

  char* ws = (char*)d_ws;
  size_t off = 0;
  auto alloc = [&](size_t bytes) -> void* {
    void* p = ws + off;
    off = (off + bytes + 255) & ~(size_t)255;
    return p;
  };

  // ~137 MiB total
  bf16* kqv_wb  = (bf16*)alloc(12288 * 2);
  bf16* proj_wb = (bf16*)alloc(262144 * 2);
  bf16* w1b     = (bf16*)alloc(1048576 * 2);
  bf16* w2b     = (bf16*)alloc(1048576 * 2);
  bf16* hb      = (bf16*)alloc((size_t)NTOK * EMB * 2);   // LN1 out; reused as y
  bf16* yb      = hb;
  float* qpb    = (float*)alloc((size_t)NROW * 32 * 4);   // reused as h2 (bf16)
  bf16* h2b     = (bf16*)qpb;
  float* kpb    = (float*)alloc((size_t)NROW * 32 * 4);   // kp; +vb reused as hid
  bf16* hidb    = (bf16*)kpb;                              // spans kpb+vb (67 MB)
  bf16* vb      = (bf16*)alloc((size_t)NROW * 64 * 2);     // contiguous after kpb
  float* partb  = (float*)alloc((size_t)512 * 2080 * 4);   // kptv partials

  // 1) weights -> bf16 (single fused launch; 4 elems/thread via float4)
  f2b4_kernel<<<1024, 256, 0, stream>>>(kqv_w, kqv_wb, 12288 / 4,
                                        proj_w, proj_wb, 262144 / 4,
                                        mlp_w1, w1b, 1048576 / 4,
                                        mlp_w2, w2b, 1048576 / 4);

  // 2) LN1: x -> h (bf16)
  ln_kernel<<<NTOK / 4, 256, 0, stream>>>(x, ln1_g, ln1_b, hb);

  // 3) fused KQV GEMM + prm_exp -> kp, qp (fp32), v (bf16), per-(b,h) layouts
  kqv_prm_kernel<<<NROW / 64, 256, 0, stream>>>(hb, kqv_wb, kqv_b, w, kpb, qpb, vb);

  // 4) kptv + kp_sum partials (no atomics, no memset)
  kptv_kernel<<<dim3(64, 8), 256, 0, stream>>>(vb, kpb, partb);

  // 5) y (bf16, token-major [NTOK, 512]) -> reuses hb; sums partials inline
  y_kernel<<<dim3(64, 8), 256, 0, stream>>>(qpb, partb, yb);

  // 6) proj GEMM + residual: d_out = y @ proj_w^T + proj_b + x
  gemm_bt<128, 128, 2, 2, 1><<<dim3(4, NTOK / 128), 256, 0, stream>>>(
      yb, proj_wb, proj_b, x, out, nullptr, NTOK, 512, 512);

  // 7) LN2: d_out -> h2 (bf16, reuses qp region)
  ln_kernel<<<NTOK / 4, 256, 0, stream>>>(out, ln2_g, ln2_b, h2b);

  // 8) MLP in 2 token-chunks of 16384 (hid reuses kp+v regions, 67 MB)
  for (int c = 0; c < 2; ++c) {
    const bf16* h2c = h2b + (size_t)c * 16384 * 512;
    float* outc = out + (size_t)c * 16384 * 512;
    gemm_bt<128, 128, 2, 2, 2><<<dim3(16, 128), 256, 0, stream>>>(
        h2c, w1b, mlp_b1, nullptr, nullptr, hidb, 16384, 2048, 512);
    gemm_bt<128, 128, 2, 2, 1><<<dim3(4, 128), 256, 0, stream>>>(
        hidb, w2b, mlp_b2, outc, outc, nullptr, 16384, 512, 2048);
  }
}